// Round 7
// baseline (358.269 us; speedup 1.0000x reference)
//
#include <hip/hip_runtime.h>
#include <math.h>

// ---------------------------------------------------------------------------
// Fused "Attention_46566035423271" for MI355X (gfx950). All fp32.
// C=64, H=W=256, HEADS=4 (2 per branch), HD=16, SR=8, WS=8, SCALE=0.25.
//
// Local branch lives in "faithful view" coords: T = A*256+B = 2h+n
// (h=true row, n=head). ATT2/S8 are keyed by T; k_proj reads T-keys.
//
// 6 dispatches: k_lin, k_dw, k_sr, k_kv1(+stats), k_attn(attn1+attn2 merged),
// k_proj(+mask).
//
// Workspace layout (float offsets). REGION0 [0, 4M) is time-shared:
//   LEP (k_lin -> k_dw), then X1 (k_attn -> k_proj) at +0 and
//   ATT2 (k_attn -> k_proj) at +2M. Safe by stream order.
//   LEP   : lepe linear output, (C,H,W)            4,194,304  @ 0
//   X1    : global-branch out, (h,w,32)            2,097,152  @ 0        (reuse)
//   ATT2  : local-branch out, (T,d,w)              2,097,152  @ 2,097,152 (reuse)
//   CONV  : depthwise-conv output, (C,H,W)         4,194,304  @ 4,194,304
//   XS    : SR-conv output, (p=1024, o=64)            65,536  @ 8,388,608
//   KS/VS : kv1 small K/V, (i,n,j,d)=(32,2,32,16)  2x 32,768  @ 8,454,272
//   Q1/Q2 : q linears, (h,n,d,w)=(256,2,16,256)  2x 2,097,152 @ 8,519,808
//   GM    : global mask partial, (h,32)                 8,192 @ 12,714,112
//   S8    : local mask partial, (T,wi,k)=(512,32,8)   131,072 @ 12,722,304
// Total = 12,853,376 floats = 51.4 MB
// ---------------------------------------------------------------------------

#define LEP   0
#define X1O   0
#define ATT2O 2097152
#define CONV  4194304
#define XS    8388608
#define KS    8454272
#define VS    8487040
#define Q1O   8519808
#define Q2O   10616960
#define GMO   12714112
#define S8O   12722304

// ===== per-pixel linears on x: lepe(64) + q1(32) + q2(32).
// grid 512: block (h = bi>>1) computes output half (bi&1) -> 2 waves/SIMD.
// weights read via wave-uniform addresses (scalar loads); x column in VGPRs.
__global__ __launch_bounds__(256) void k_lin(
    const float* __restrict__ x, const float* __restrict__ w_lepe,
    const float* __restrict__ b_lepe, const float* __restrict__ w_q1,
    const float* __restrict__ w_q2, float* __restrict__ ws) {
  const int h = blockIdx.x >> 1, half = blockIdx.x & 1, t = threadIdx.x;
  float xv[64];
  const float* xp = x + h * 256 + t;
#pragma unroll
  for (int c = 0; c < 64; ++c) xv[c] = xp[c * 65536];
  const int og0 = half * 64;
  for (int og = og0; og < og0 + 64; og += 4) {
    const float* wr;
    if (og < 64)      wr = w_lepe + og * 64;
    else if (og < 96) wr = w_q1 + (og - 64) * 64;
    else              wr = w_q2 + (og - 96) * 64;
    float a0 = 0.f, a1 = 0.f, a2 = 0.f, a3 = 0.f;
#pragma unroll
    for (int c = 0; c < 64; ++c) {
      float xc = xv[c];
      a0 = fmaf(xc, wr[c], a0);
      a1 = fmaf(xc, wr[64 + c], a1);
      a2 = fmaf(xc, wr[128 + c], a2);
      a3 = fmaf(xc, wr[192 + c], a3);
    }
    float acc[4] = {a0, a1, a2, a3};
#pragma unroll
    for (int k = 0; k < 4; ++k) {
      int o = og + k;
      if (o < 64) {
        ws[LEP + o * 65536 + h * 256 + t] = acc[k] + b_lepe[o];
      } else if (o < 96) {
        int oo = o - 64;  // n = oo>>4, d = oo&15 ; layout [h][n][d][w]
        ws[Q1O + h * 8192 + (oo >> 4) * 4096 + (oo & 15) * 256 + t] = acc[k];
      } else {
        int oo = o - 96;
        ws[Q2O + h * 8192 + (oo >> 4) * 4096 + (oo & 15) * 256 + t] = acc[k];
      }
    }
  }
}

// ===== depthwise 3x3 SAME conv on LEP -> CONV (+kb_lepe). block = (channel, 32-row tile)
__global__ __launch_bounds__(256) void k_dw(const float* __restrict__ klepe,
                                            const float* __restrict__ kb,
                                            float* ws) {
  const int c = blockIdx.x >> 3, r0 = (blockIdx.x & 7) * 32, t = threadIdx.x;
  __shared__ float s[34][256];
  const float* src = ws + LEP + c * 65536;
  for (int i = 0; i < 34; ++i) {
    int r = r0 - 1 + i;
    s[i][t] = (r >= 0 && r < 256) ? src[r * 256 + t] : 0.0f;
  }
  const float k00 = klepe[c * 9 + 0], k01 = klepe[c * 9 + 1], k02 = klepe[c * 9 + 2];
  const float k10 = klepe[c * 9 + 3], k11 = klepe[c * 9 + 4], k12 = klepe[c * 9 + 5];
  const float k20 = klepe[c * 9 + 6], k21 = klepe[c * 9 + 7], k22 = klepe[c * 9 + 8];
  const float bias = kb[c];
  __syncthreads();
  float* dst = ws + CONV + c * 65536;
  for (int rr = 0; rr < 32; ++rr) {
    float acc = bias;
    {
      const float* r_ = s[rr];
      float l = (t > 0) ? r_[t - 1] : 0.f, m = r_[t], g = (t < 255) ? r_[t + 1] : 0.f;
      acc = fmaf(l, k00, fmaf(m, k01, fmaf(g, k02, acc)));
    }
    {
      const float* r_ = s[rr + 1];
      float l = (t > 0) ? r_[t - 1] : 0.f, m = r_[t], g = (t < 255) ? r_[t + 1] : 0.f;
      acc = fmaf(l, k10, fmaf(m, k11, fmaf(g, k12, acc)));
    }
    {
      const float* r_ = s[rr + 2];
      float l = (t > 0) ? r_[t - 1] : 0.f, m = r_[t], g = (t < 255) ? r_[t + 1] : 0.f;
      acc = fmaf(l, k20, fmaf(m, k21, fmaf(g, k22, acc)));
    }
    dst[(r0 + rr) * 256 + t] = acc;
  }
}

// ===== SR conv as GEMM: out[p][o] = sum_K patch[p][K] * w_sr[o][K], K=4096.
// block = 4 pixels x 64 outputs; K split across the 4 waves; LDS reduce.
__global__ __launch_bounds__(256) void k_sr(const float* __restrict__ x,
                                            const float* __restrict__ w_sr,
                                            const float* __restrict__ b_sr,
                                            float* ws) {
  const int blk = blockIdx.x, t = threadIdx.x;
  __shared__ float patch[4 * 4100];
  __shared__ float red[1024];
  for (int idx = t; idx < 16384; idx += 256) {
    int px = idx >> 12, kk = idx & 4095;
    int pix = blk * 4 + px;
    int i = pix >> 5, j = pix & 31;
    int c = kk >> 6, dy = (kk >> 3) & 7, dx = kk & 7;
    patch[px * 4100 + kk] = x[c * 65536 + (i * 8 + dy) * 256 + j * 8 + dx];
  }
  __syncthreads();
  const int p = t & 3, oq = (t >> 2) & 15, k2i = t >> 6;
  const int o0 = oq * 4;
  const float* w0 = w_sr + (o0 + 0) * 4096;
  const float* w1 = w_sr + (o0 + 1) * 4096;
  const float* w2 = w_sr + (o0 + 2) * 4096;
  const float* w3 = w_sr + (o0 + 3) * 4096;
  const float* pb = &patch[p * 4100];
  float a0 = 0.f, a1 = 0.f, a2 = 0.f, a3 = 0.f;
  for (int K = k2i * 1024; K < k2i * 1024 + 1024; K += 4) {
    float4 pv = *(const float4*)&pb[K];
    float4 u0 = *(const float4*)&w0[K];
    float4 u1 = *(const float4*)&w1[K];
    float4 u2 = *(const float4*)&w2[K];
    float4 u3 = *(const float4*)&w3[K];
    a0 = fmaf(pv.x, u0.x, fmaf(pv.y, u0.y, fmaf(pv.z, u0.z, fmaf(pv.w, u0.w, a0))));
    a1 = fmaf(pv.x, u1.x, fmaf(pv.y, u1.y, fmaf(pv.z, u1.z, fmaf(pv.w, u1.w, a1))));
    a2 = fmaf(pv.x, u2.x, fmaf(pv.y, u2.y, fmaf(pv.z, u2.z, fmaf(pv.w, u2.w, a2))));
    a3 = fmaf(pv.x, u3.x, fmaf(pv.y, u3.y, fmaf(pv.z, u3.z, fmaf(pv.w, u3.w, a3))));
  }
  red[p * 256 + (o0 + 0) * 4 + k2i] = a0;
  red[p * 256 + (o0 + 1) * 4 + k2i] = a1;
  red[p * 256 + (o0 + 2) * 4 + k2i] = a2;
  red[p * 256 + (o0 + 3) * 4 + k2i] = a3;
  __syncthreads();
  {
    int p2 = t >> 6, o = t & 63;
    float v = red[p2 * 256 + o * 4 + 0] + red[p2 * 256 + o * 4 + 1] +
              red[p2 * 256 + o * 4 + 2] + red[p2 * 256 + o * 4 + 3];
    v += b_sr[o];
    int pix = blk * 4 + p2;
    ws[XS + pix * 64 + o] = v;  // (p, o)
  }
}

// ===== kv1 (+ fused ada_iln stats): normalize+gelu XS then 64->64 linear.
// Each block recomputes the stats deterministically (identical order) ->
// no grid-1 stats kernel. Writes K/V small (i,n,j,d).
__global__ __launch_bounds__(256) void k_kv1(const float* __restrict__ gamma,
                                             const float* __restrict__ beta,
                                             const float* __restrict__ rho,
                                             const float* __restrict__ w_kv1,
                                             float* ws) {
  const int blk = blockIdx.x, t = threadIdx.x;  // grid 16, 64 tokens/block
  __shared__ float xn_l[64 * 65];
  __shared__ float A_s[64], B_s[64];
  __shared__ float ls[4][64], lq[4][64];
  // --- stats (replicated per block; deterministic identical math) ---
  {
    const int o = t & 63, g = t >> 6;
    const float* xs = ws + XS;
    float s = 0.f, sq = 0.f;
    for (int p = g * 256; p < g * 256 + 256; ++p) {
      float v = xs[p * 64 + o];
      s += v;
      sq = fmaf(v, v, sq);
    }
    ls[g][o] = s;
    lq[g][o] = sq;
    __syncthreads();
    if (t < 64) {
      float cs = ls[0][t] + ls[1][t] + ls[2][t] + ls[3][t];
      float cq = lq[0][t] + lq[1][t] + lq[2][t] + lq[3][t];
      float mu_in = cs * (1.0f / 1024.0f);
      float var_in = cq * (1.0f / 1024.0f) - mu_in * mu_in;
      float gs = cs, gq = cq;
      gs += __shfl_xor(gs, 1);  gq += __shfl_xor(gq, 1);
      gs += __shfl_xor(gs, 2);  gq += __shfl_xor(gq, 2);
      gs += __shfl_xor(gs, 4);  gq += __shfl_xor(gq, 4);
      gs += __shfl_xor(gs, 8);  gq += __shfl_xor(gq, 8);
      gs += __shfl_xor(gs, 16); gq += __shfl_xor(gq, 16);
      gs += __shfl_xor(gs, 32); gq += __shfl_xor(gq, 32);
      float mu_ln = gs * (1.0f / 65536.0f);
      float var_ln = gq * (1.0f / 65536.0f) - mu_ln * mu_ln;
      float rs_in = 1.0f / sqrtf(var_in + 1e-5f);
      float rs_ln = 1.0f / sqrtf(var_ln + 1e-5f);
      float r = rho[t], ga = gamma[t], be = beta[t];
      float coef = r * rs_in + (1.0f - r) * rs_ln;
      float offs = -(r * mu_in * rs_in + (1.0f - r) * mu_ln * rs_ln);
      A_s[t] = coef * ga;
      B_s[t] = offs * ga + be;
    }
    __syncthreads();
  }
  // --- normalize + exact gelu into LDS ---
  for (int idx = t; idx < 4096; idx += 256) {
    int jl = idx >> 6, c = idx & 63;
    float v = ws[XS + (blk * 64 + jl) * 64 + c];
    v = v * A_s[c] + B_s[c];
    v = 0.5f * v * (1.0f + erff(v * 0.70710678118654752440f));
    xn_l[jl * 65 + c] = v;
  }
  __syncthreads();
  const int j = t & 63, w = t >> 6;
  float xr[64];
#pragma unroll
  for (int c = 0; c < 64; ++c) xr[c] = xn_l[j * 65 + c];
  const int pg = blk * 64 + j;
  const int ii = pg >> 5, jj = pg & 31;
  for (int oc = w * 16; oc < w * 16 + 16; ++oc) {
    const float* wr = w_kv1 + oc * 64;
    float acc = 0.f;
#pragma unroll
    for (int c = 0; c < 64; ++c) acc = fmaf(xr[c], wr[c], acc);
    int nn = (oc >> 4) & 1, dd = oc & 15;
    int base = (oc < 32) ? KS : VS;
    ws[base + ((ii * 2 + nn) * 32 + jj) * 16 + dd] = acc;
  }
}

// ===== merged attention: blocks 0..255 = global branch (h = bid),
// blocks 256..767 = local branch (b = bid-256). Branch is block-uniform;
// LDS is a union overlay (attn2's 8704 floats is the max).
__global__ __launch_bounds__(256) void k_attn(const float* __restrict__ x,
                                              const float* __restrict__ w_kv2,
                                              float* ws) {
  __shared__ float smem[8704];
  const int t = threadIdx.x;
  if (blockIdx.x < 256) {
    // ---------------- attn1 (global branch), h = blockIdx.x ----------------
    const int h = blockIdx.x;
    const int i = h & 31;
    float* k_l = smem;            // [1024]
    float* v_l = smem + 1024;     // [1024]
    float* msum = smem + 2048;    // [4*32] per-wave slots, deterministic
    for (int idx = t; idx < 1024; idx += 256) {
      k_l[idx] = ws[KS + i * 1024 + idx];
      v_l[idx] = ws[VS + i * 1024 + idx];
    }
    __syncthreads();
    const float* qb = ws + Q1O + h * 8192;
    float psum[32];
#pragma unroll
    for (int j = 0; j < 32; ++j) psum[j] = 0.f;
#pragma unroll 1
    for (int n = 0; n < 2; ++n) {
      float q[16];
#pragma unroll
      for (int d = 0; d < 16; ++d) q[d] = qb[(n * 16 + d) * 256 + t];
      float s[32];
      float m = -1e30f;
#pragma unroll
      for (int j = 0; j < 32; ++j) {
        const float4* kr = (const float4*)&k_l[(n * 32 + j) * 16];
        float4 c0 = kr[0], c1 = kr[1], c2 = kr[2], c3 = kr[3];
        float a =
            fmaf(q[0], c0.x, fmaf(q[1], c0.y, fmaf(q[2], c0.z, fmaf(q[3], c0.w,
            fmaf(q[4], c1.x, fmaf(q[5], c1.y, fmaf(q[6], c1.z, fmaf(q[7], c1.w,
            fmaf(q[8], c2.x, fmaf(q[9], c2.y, fmaf(q[10], c2.z, fmaf(q[11], c2.w,
            fmaf(q[12], c3.x, fmaf(q[13], c3.y, fmaf(q[14], c3.z,
                 q[15] * c3.w)))))))))))))));
        a *= 0.25f;
        s[j] = a;
        m = fmaxf(m, a);
      }
      float z = 0.f;
#pragma unroll
      for (int j = 0; j < 32; ++j) {
        float e = expf(s[j] - m);
        s[j] = e;
        z += e;
      }
      float rz = 1.0f / z;
      float4 o0 = {0, 0, 0, 0}, o1 = {0, 0, 0, 0}, o2 = {0, 0, 0, 0}, o3 = {0, 0, 0, 0};
#pragma unroll
      for (int j = 0; j < 32; ++j) {
        float pj = s[j] * rz;
        psum[j] += pj;
        const float4* vr = (const float4*)&v_l[(n * 32 + j) * 16];
        float4 v0 = vr[0], v1 = vr[1], v2 = vr[2], v3 = vr[3];
        o0.x = fmaf(pj, v0.x, o0.x); o0.y = fmaf(pj, v0.y, o0.y);
        o0.z = fmaf(pj, v0.z, o0.z); o0.w = fmaf(pj, v0.w, o0.w);
        o1.x = fmaf(pj, v1.x, o1.x); o1.y = fmaf(pj, v1.y, o1.y);
        o1.z = fmaf(pj, v1.z, o1.z); o1.w = fmaf(pj, v1.w, o1.w);
        o2.x = fmaf(pj, v2.x, o2.x); o2.y = fmaf(pj, v2.y, o2.y);
        o2.z = fmaf(pj, v2.z, o2.z); o2.w = fmaf(pj, v2.w, o2.w);
        o3.x = fmaf(pj, v3.x, o3.x); o3.y = fmaf(pj, v3.y, o3.y);
        o3.z = fmaf(pj, v3.z, o3.z); o3.w = fmaf(pj, v3.w, o3.w);
      }
      float4* xo = (float4*)&ws[X1O + (h * 256 + t) * 32 + n * 16];
      xo[0] = o0; xo[1] = o1; xo[2] = o2; xo[3] = o3;
    }
    const int wid = t >> 6;
#pragma unroll
    for (int j = 0; j < 32; ++j) {
      float v = psum[j];
      v += __shfl_xor(v, 1);  v += __shfl_xor(v, 2);  v += __shfl_xor(v, 4);
      v += __shfl_xor(v, 8);  v += __shfl_xor(v, 16); v += __shfl_xor(v, 32);
      if ((t & 63) == 0) msum[wid * 32 + j] = v;
    }
    __syncthreads();
    if (t < 32)
      ws[GMO + h * 32 + t] =
          (msum[t] + msum[32 + t] + msum[64 + t] + msum[96 + t]) * (1.0f / 4096.0f);
  } else {
    // ---------------- attn2 (local branch), b = blockIdx.x - 256 ----------------
    const int b = blockIdx.x - 256;
    const int h = b >> 1, n = b & 1;
    float* k2 = smem;           // [256*17]
    float* v2 = smem + 4352;    // [256*17]
    {
      const float* src = x + (h >> 2) * 65536 + ((h & 3) * 64) * 256;
      float xr[64];
#pragma unroll
      for (int c = 0; c < 64; ++c) xr[c] = src[c * 256 + t];
      const float* wk = w_kv2 + (n * 16) * 64;
      const float* wv = w_kv2 + (32 + n * 16) * 64;
#pragma unroll 2
      for (int d = 0; d < 16; ++d) {
        float ak = 0.f, av = 0.f;
#pragma unroll
        for (int c = 0; c < 64; ++c) {
          ak = fmaf(xr[c], wk[d * 64 + c], ak);
          av = fmaf(xr[c], wv[d * 64 + c], av);
        }
        k2[t * 17 + d] = ak;
        v2[t * 17 + d] = av;
      }
    }
    __syncthreads();
    const int wi = t >> 3;
    const float* qb = ws + Q2O + h * 8192 + n * 4096;
    float qv[16];
#pragma unroll
    for (int d = 0; d < 16; ++d) qv[d] = qb[d * 256 + t];
    float s[8];
    float m = -1e30f;
#pragma unroll
    for (int j = 0; j < 8; ++j) {
      const float* kr = &k2[(wi * 8 + j) * 17];
      float a = 0.f;
#pragma unroll
      for (int d = 0; d < 16; ++d) a = fmaf(qv[d], kr[d], a);
      a *= 0.25f;
      s[j] = a;
      m = fmaxf(m, a);
    }
    float z = 0.f;
#pragma unroll
    for (int j = 0; j < 8; ++j) {
      float e = expf(s[j] - m);
      s[j] = e;
      z += e;
    }
    float rz = 1.0f / z;
#pragma unroll
    for (int j = 0; j < 8; ++j) s[j] *= rz;
    float o[16];
#pragma unroll
    for (int d = 0; d < 16; ++d) o[d] = 0.f;
#pragma unroll
    for (int j = 0; j < 8; ++j) {
      const float* vr = &v2[(wi * 8 + j) * 17];
      float pj = s[j];
#pragma unroll
      for (int d = 0; d < 16; ++d) o[d] = fmaf(pj, vr[d], o[d]);
    }
#pragma unroll
    for (int d = 0; d < 16; ++d) ws[ATT2O + (b * 16 + d) * 256 + t] = o[d];
#pragma unroll
    for (int j = 0; j < 8; ++j) {
      float v = s[j];
      v += __shfl_xor(v, 1);
      v += __shfl_xor(v, 2);
      v += __shfl_xor(v, 4);
      if ((t & 7) == 0) ws[S8O + (b * 32 + wi) * 8 + j] = v;
    }
  }
}

// ===== final: fused mask write + cat(x1, scrambled x2) + scrambled lepe,
// then 64x64 proj + bias. Block a == mask row r = a.
__global__ __launch_bounds__(256) void k_proj(const float* __restrict__ w_proj,
                                              const float* __restrict__ b_proj,
                                              float* ws, float* __restrict__ out) {
  const int a = blockIdx.x, t = threadIdx.x;
  // --- mask (was k_mask): lm row B=a, col=t; + tiled global mask ---
  {
    float gm = ws[GMO + a * 32 + (t & 31)];
    float lm = (ws[S8O + a * 256 + t] +
                ws[S8O + (256 + a) * 256 + t]) * 0.0625f;
    float val = lm + gm;
    out[4194304 + a * 256 + t] = val;           // mask_1 (row-major)
    out[4194304 + 65536 + t * 256 + a] = val;   // mask_2 (transposed)
  }
  __shared__ float cat[256 * 65];
  for (int idx = t; idx < 8192; idx += 256) {
    int bcol = idx >> 5, c = idx & 31;
    cat[bcol * 65 + c] = ws[X1O + (a * 256 + bcol) * 32 + c];
  }
  const int np = a >> 7, d = (a >> 3) & 15;
  for (int idx = t; idx < 8192; idx += 256) {
    int bcol = idx >> 5, e = idx & 31;
    int hp = (a & 7) * 32 + (bcol >> 3);
    cat[bcol * 65 + 32 + e] =
        ws[ATT2O + ((np * 256 + hp) * 16 + d) * 256 + (bcol & 7) * 32 + e];
  }
  __syncthreads();
  // lepe[a][b][c] = conv_out[a>>2][(a&3)*64 + c][b]  (contiguous 64KB slab)
  const float* conv = ws + CONV + (a >> 2) * 65536 + ((a & 3) * 64) * 256;
  for (int idx = t; idx < 16384; idx += 256) {
    int c = idx >> 8, bcol = idx & 255;
    cat[bcol * 65 + c] += conv[c * 256 + bcol];
  }
  __syncthreads();
  float xr[64];
#pragma unroll
  for (int c = 0; c < 64; ++c) xr[c] = cat[t * 65 + c];
  float* op = out + (a * 256 + t) * 64;
  for (int og = 0; og < 64; og += 4) {
    const float* w0 = w_proj + og * 64;
    float a0 = b_proj[og], a1 = b_proj[og + 1], a2 = b_proj[og + 2], a3 = b_proj[og + 3];
#pragma unroll
    for (int c = 0; c < 64; ++c) {
      float xc = xr[c];
      a0 = fmaf(xc, w0[c], a0);
      a1 = fmaf(xc, w0[64 + c], a1);
      a2 = fmaf(xc, w0[128 + c], a2);
      a3 = fmaf(xc, w0[192 + c], a3);
    }
    float4 rv;
    rv.x = a0; rv.y = a1; rv.z = a2; rv.w = a3;
    *(float4*)(op + og) = rv;
  }
}

extern "C" void kernel_launch(void* const* d_in, const int* in_sizes, int n_in,
                              void* d_out, int out_size, void* d_ws, size_t ws_size,
                              hipStream_t stream) {
  const float* x       = (const float*)d_in[0];
  const float* gamma   = (const float*)d_in[1];
  const float* beta    = (const float*)d_in[2];
  const float* rho     = (const float*)d_in[3];
  const float* w_lepe  = (const float*)d_in[4];
  const float* b_lepe  = (const float*)d_in[5];
  const float* k_lepe  = (const float*)d_in[6];
  const float* kb_lepe = (const float*)d_in[7];
  const float* w_sr    = (const float*)d_in[8];
  const float* b_sr    = (const float*)d_in[9];
  const float* w_q1    = (const float*)d_in[10];
  const float* w_kv1   = (const float*)d_in[11];
  const float* w_q2    = (const float*)d_in[12];
  const float* w_kv2   = (const float*)d_in[13];
  const float* w_proj  = (const float*)d_in[14];
  const float* b_proj  = (const float*)d_in[15];
  float* ws  = (float*)d_ws;
  float* out = (float*)d_out;

  hipLaunchKernelGGL(k_lin,   dim3(512), dim3(256), 0, stream, x, w_lepe, b_lepe, w_q1, w_q2, ws);
  hipLaunchKernelGGL(k_dw,    dim3(512), dim3(256), 0, stream, k_lepe, kb_lepe, ws);
  hipLaunchKernelGGL(k_sr,    dim3(256), dim3(256), 0, stream, x, w_sr, b_sr, ws);
  hipLaunchKernelGGL(k_kv1,   dim3(16),  dim3(256), 0, stream, gamma, beta, rho, w_kv1, ws);
  hipLaunchKernelGGL(k_attn,  dim3(768), dim3(256), 0, stream, x, w_kv2, ws);
  hipLaunchKernelGGL(k_proj,  dim3(256), dim3(256), 0, stream, w_proj, b_proj, ws, out);
}